// Round 9
// baseline (636.868 us; speedup 1.0000x reference)
//
#include <hip/hip_runtime.h>
#include <cstdint>
#include <cstddef>

// R14: wave-specialized dual-group persistent GRU. 256 blocks x 512 thr,
// 1 block/CU (LDS padded >80KB => exactly 32 blocks/XCD, R11-validated).
// Each XCD's 32 blocks serve BOTH of its sample groups: waves 0-3 = group A
// (xcc*2), waves 4-7 = group B (xcc*2+1) -> each SIMD hosts one A-wave and
// one B-wave. While one group's waves poll the step barrier, the other
// group's waves compute: the ~11us/step stall measured in R11/R12 is covered
// by independent work. Waves are self-contained (wave-private hstore/xs);
// steady loop has NO __syncthreads -- per-wave arrive+poll on per-group
// monotonic tickets (128 waves/group/round). Geometry/swizzles/layouts are
// verbatim from R13 (passed correctness); gi-in-registers pre-GEMM from R12.

typedef __attribute__((ext_vector_type(8))) _Float16 f16x8;
typedef __attribute__((ext_vector_type(4))) float floatx4;

__device__ unsigned g_cnt[8 * 64];     // per-XCD registration tickets
__device__ unsigned g_gbar[16 * 64];   // per-group round tickets (padded)

// h[t]: [16 grp][32 cgrp][256 rows][16 cols] fp16 = 4MB. P[t]: [16][32][512] f32.
__device__ __align__(256) _Float16 g_h[12][16 * 32 * 256 * 16];
__device__ __align__(256) float    g_P[12][16 * 32 * 512];

__device__ __forceinline__ float sigm_f(float v) { return 1.0f / (1.0f + __expf(-v)); }
__device__ __forceinline__ float tanh_f(float v) { return 2.0f / (1.0f + __expf(-2.0f * v)) - 1.0f; }

__device__ __forceinline__ void async16(void* lds, const void* g) {
    __builtin_amdgcn_global_load_lds(
        (const __attribute__((address_space(1))) void*)g,
        (__attribute__((address_space(3))) void*)lds, 16, 0, 0);
}

// Per-WAVE arrive+wait: 128 waves per group per round (32 blocks x 4 waves).
// vmcnt(0) drains this wave's stores to L2 before arrival; monotonic ticket
// is replay-safe (13 rounds x 128 = 1664 per launch, multiple of 128).
__device__ __forceinline__ void wave_arrive_wait(unsigned grp) {
    asm volatile("s_waitcnt vmcnt(0)" ::: "memory");
    if ((threadIdx.x & 63) == 0) {
        unsigned* ctr = &g_gbar[grp * 64];
        unsigned t = __hip_atomic_fetch_add(ctr, 1u, __ATOMIC_RELAXED,
                                            __HIP_MEMORY_SCOPE_AGENT);
        unsigned tgt = (t & ~127u) + 128u;
        while (__hip_atomic_load(ctr, __ATOMIC_RELAXED,
                                 __HIP_MEMORY_SCOPE_AGENT) < tgt)
            __builtin_amdgcn_s_sleep(1);
    }
    asm volatile("" ::: "memory");   // compiler fence: no hoisting loads above poll
}

// ---------------- K0: casts + packing + a0 (unchanged, validated) ----------------
__global__ __launch_bounds__(256) void k0_prep(
    const float* __restrict__ z, const float* __restrict__ x,
    const float* __restrict__ x0, const float* __restrict__ W_ia,
    const float* __restrict__ b_ia, const float* __restrict__ W_ih,
    const float* __restrict__ W_hh, const float* __restrict__ W_h0,
    const float* __restrict__ W_out, const float* __restrict__ b_hh,
    _Float16* __restrict__ zx16, _Float16* __restrict__ wcat16,
    _Float16* __restrict__ whh16, float* __restrict__ pk, float* __restrict__ xbuf)
{
    const int ZX = 4096 * 256, WC = 2048 * 256, WH = 1536 * 512, PKN = 512, XB = 4096 * 2;
    const int total = ZX + WC + WH + PKN + XB;
    for (int idx = blockIdx.x * 256 + threadIdx.x; idx < total; idx += gridDim.x * 256) {
        if (idx < ZX) {
            int i = idx >> 8, k = idx & 255;
            float v = (k < 128) ? z[i * 128 + k] : x[i * 128 + (k - 128)];
            zx16[idx] = (_Float16)v;
        } else if (idx < ZX + WC) {
            int j = idx - ZX;
            int n = j >> 8, k = j & 255;
            float v = (n < 512) ? W_h0[n * 256 + k] : W_ih[(n - 512) * 258 + k];
            wcat16[j] = (_Float16)v;
        } else if (idx < ZX + WC + WH) {
            int j = idx - ZX - WC;
            whh16[j] = (_Float16)W_hh[j];
        } else if (idx < ZX + WC + WH + PKN) {
            int jc = idx - ZX - WC - WH;
            float* o = pk + jc * 12;
            o[0] = W_ih[jc * 258 + 256];          o[1] = W_ih[jc * 258 + 257];
            o[2] = W_ih[(512 + jc) * 258 + 256];  o[3] = W_ih[(512 + jc) * 258 + 257];
            o[4] = W_ih[(1024 + jc) * 258 + 256]; o[5] = W_ih[(1024 + jc) * 258 + 257];
            o[6] = b_hh[jc]; o[7] = b_hh[512 + jc]; o[8] = b_hh[1024 + jc];
            o[9] = W_out[jc]; o[10] = W_out[512 + jc]; o[11] = 0.f;
        } else {
            int j = idx - ZX - WC - WH - PKN;
            int i = j >> 1, d = j & 1;
            float s = b_ia[d];
            #pragma unroll
            for (int k2 = 0; k2 < 4; k2++) s += x0[i * 4 + k2] * W_ia[d * 4 + k2];
            xbuf[j] = s;
        }
    }
}

// ---------------- K2: wave-specialized dual-group persistent GRU ----------------
// LDS: B @0 (48 rows x 1024 = 48KB; pre-phase 64 rows x 512 = 32KB overlaps),
// hstore @49152 (8 waves x [64][16] fp16 = 16KB), xs @65536 (8 x 512B = 4KB),
// slot @69632. Request 86016 (>80KB forces 1 block/CU).
__global__ __launch_bounds__(512, 2) void k2_wave(
    const _Float16* __restrict__ zx16, const _Float16* __restrict__ wcat16,
    const _Float16* __restrict__ whh16, const float* __restrict__ pk,
    const float* __restrict__ xbuf, const float* __restrict__ b_h0,
    const float* __restrict__ b_ih, float* __restrict__ dout,
    const float* __restrict__ b_out)
{
    extern __shared__ __align__(16) char smem[];
    const uint32_t BOFF = 0, HST = 49152, XSO = 65536, SLO = 69632;
    const int tid = threadIdx.x;

    // ---- XCD discovery + registration (1 blk/CU => exactly 32 blks/XCD) ----
    unsigned xcc;
    asm volatile("s_getreg_b32 %0, hwreg(HW_REG_XCC_ID)" : "=s"(xcc));
    xcc &= 7u;
    if (tid == 0) {
        unsigned s = __hip_atomic_fetch_add(&g_cnt[xcc * 64], 1u, __ATOMIC_RELAXED,
                                            __HIP_MEMORY_SCOPE_AGENT) & 31u;
        *(unsigned*)(smem + SLO) = s;
    }
    __syncthreads();
    const int cgrp = (int)*(volatile unsigned*)(smem + SLO);   // 0..31: col slice
    const int jc0 = cgrp * 16;

    const int wv = tid >> 6, lane = tid & 63;
    const int l15 = lane & 15, q2 = lane >> 4;
    const unsigned grp = xcc * 2u + (unsigned)(wv >> 2);  // wave's sample group
    const int M0g = (int)grp * 256;
    const int r0 = (wv & 3) * 64;                         // wave's 64 rows

    // ---- stage pre-B: 64 rows x 256 fp16 (512B rows) from wcat16 [R13] ----
    #pragma unroll
    for (int j2 = 0; j2 < 4; j2++) {
        int p = j2 * 8 + wv;
        int r0s = p * 2;
        int r = r0s + (lane >> 5);
        int s = lane & 31;
        int n = (r < 48) ? (512 + (r >> 4) * 512 + jc0 + (r & 15))
                         : (jc0 + (r - 48));
        const _Float16* src = wcat16 + (size_t)n * 256 + ((s ^ (r & 15)) << 3);
        async16(smem + (uint32_t)r0s * 512, src);
    }

    // ---- t-invariant params ----
    const int jc = jc0 + l15;
    const float4* pkp = (const float4*)(pk + (size_t)jc * 12);
    float4 p0v = pkp[0], p1v = pkp[1], p2v = pkp[2];
    float wo0 = p2v.y, wo1 = p2v.z;
    float bh0v = b_h0[jc];
    float bih0 = b_ih[jc], bih1 = b_ih[512 + jc], bih2 = b_ih[1024 + jc];
    float bo = b_out[lane & 1];

    uint32_t bbase[3];   // steady B (48 rows x 1024B) [R13 swizzle]
    #pragma unroll
    for (int g = 0; g < 3; g++) {
        int r = g * 16 + l15;
        bbase[g] = BOFF + (uint32_t)r * 1024 +
                   ((uint32_t)(q2 ^ (r & 3)) << 4) + ((uint32_t)((r >> 2) & 3) << 6);
    }
    uint32_t pb[4];      // pre-B (64 rows x 512B): 0..2 gates, 3 h0 [R13]
    #pragma unroll
    for (int sl = 0; sl < 4; sl++) {
        int r = (sl < 3) ? (sl * 16 + l15) : (48 + l15);
        pb[sl] = BOFF + (uint32_t)r * 512 +
                 ((uint32_t)(q2 ^ (r & 3)) << 4) + ((uint32_t)((r >> 2) & 3) << 6);
    }
    __syncthreads();   // pre-B staged (compiler drains vmcnt at barrier)

    // ---- pre-GEMM: K=256, A=zx16 rows r0..r0+63, 4 mt tiles [R13 geometry] ----
    floatx4 accP[4][4];
    #pragma unroll
    for (int mt = 0; mt < 4; mt++)
        #pragma unroll
        for (int sl = 0; sl < 4; sl++) accP[mt][sl] = (floatx4){0.f, 0.f, 0.f, 0.f};
    {
        const char* zp[4];
        #pragma unroll
        for (int mt = 0; mt < 4; mt++)
            zp[mt] = (const char*)zx16 +
                ((size_t)(M0g + r0 + mt * 16 + l15) * 512) + (size_t)q2 * 16;
        f16x8 aq[2][4];
        #define ALOADZ(S, KS) do { \
            aq[S][0] = *(const f16x8*)(zp[0] + (KS) * 64); \
            aq[S][1] = *(const f16x8*)(zp[1] + (KS) * 64); \
            aq[S][2] = *(const f16x8*)(zp[2] + (KS) * 64); \
            aq[S][3] = *(const f16x8*)(zp[3] + (KS) * 64); \
        } while (0)
        ALOADZ(0, 0); ALOADZ(1, 1);
        #pragma unroll
        for (int ks = 0; ks < 8; ks++) {
            f16x8 a0 = aq[ks & 1][0], a1 = aq[ks & 1][1];
            f16x8 a2 = aq[ks & 1][2], a3 = aq[ks & 1][3];
            if (ks < 6) { ALOADZ(ks & 1, ks + 2); }
            const uint32_t kadd = (uint32_t)((ks >> 2) << 8);
            const uint32_t kxor = (uint32_t)((ks & 3) << 6);
            #pragma unroll
            for (int sl = 0; sl < 4; sl++) {
                f16x8 b = *(const f16x8*)(smem + ((pb[sl] + kadd) ^ kxor));
                accP[0][sl] = __builtin_amdgcn_mfma_f32_16x16x32_f16(a0, b, accP[0][sl], 0, 0, 0);
                accP[1][sl] = __builtin_amdgcn_mfma_f32_16x16x32_f16(a1, b, accP[1][sl], 0, 0, 0);
                accP[2][sl] = __builtin_amdgcn_mfma_f32_16x16x32_f16(a2, b, accP[2][sl], 0, 0, 0);
                accP[3][sl] = __builtin_amdgcn_mfma_f32_16x16x32_f16(a3, b, accP[3][sl], 0, 0, 0);
            }
        }
        #undef ALOADZ
    }

    // ---- gi -> registers (+bias); h0 -> wave-private hstore ----
    float gi0[4][4], gi1[4][4], gi2[4][4];
    #pragma unroll
    for (int mt = 0; mt < 4; mt++)
        #pragma unroll
        for (int reg = 0; reg < 4; reg++) {
            gi0[mt][reg] = accP[mt][0][reg] + bih0;
            gi1[mt][reg] = accP[mt][1][reg] + bih1;
            gi2[mt][reg] = accP[mt][2][reg] + bih2;
        }
    #pragma unroll
    for (int mt = 0; mt < 4; mt++)
        #pragma unroll
        for (int reg = 0; reg < 4; reg++) {
            int rl = mt * 16 + q2 * 4 + reg;   // 0..63 within wave slice
            *(_Float16*)(smem + HST + (uint32_t)(wv * 2048 + rl * 32 + l15 * 2)) =
                (_Float16)(accP[mt][3][reg] + bh0v);
        }
    __syncthreads();   // all pre-B reads done before W_hh overwrites region

    // ---- stage W_hh (48 rows x 512 = 48KB) [R13] ----
    #pragma unroll
    for (int j = 0; j < 6; j++) {
        int r = j * 8 + wv;
        int n = (r >> 4) * 512 + jc0 + (r & 15);
        const _Float16* src = whh16 + (size_t)n * 512 + ((lane ^ (r & 15)) << 3);
        async16(smem + BOFF + (uint32_t)r * 1024, src);
    }
    // ---- publish h0 (wave's 64x16 slice, contiguous 2KB) ----
    #pragma unroll
    for (int p = 0; p < 2; p++) {
        int row = (lane >> 1) + p * 32;
        f16x8 hv = *(const f16x8*)(smem + HST + (uint32_t)(wv * 2048 + row * 32 + (lane & 1) * 16));
        *(f16x8*)((char*)&g_h[0][0] + (size_t)grp * 262144 + (size_t)cgrp * 8192 +
                  (size_t)(r0 + row) * 32 + (size_t)(lane & 1) * 16) = hv;
    }
    wave_arrive_wait(grp);   // round 0 (h0); also drains W_hh staging
    __syncthreads();         // all waves' W_hh staged before B reads

    // ---- 12-step loop: NO __syncthreads inside ----
    #pragma unroll 1
    for (int t = 0; t < 12; t++) {
        // GEMM: K=512, A from g_h[t] (block-major layout, R13 formula)
        const char* hb = (const char*)&g_h[t][0] + (size_t)grp * 262144 +
                         (size_t)(q2 >> 1) * 8192 + (size_t)(q2 & 1) * 16;
        const char* rp[4];
        #pragma unroll
        for (int mt = 0; mt < 4; mt++)
            rp[mt] = hb + (size_t)(r0 + mt * 16 + l15) * 32;
        floatx4 acc[4][3];
        #pragma unroll
        for (int mt = 0; mt < 4; mt++)
            #pragma unroll
            for (int g = 0; g < 3; g++) acc[mt][g] = (floatx4){0.f, 0.f, 0.f, 0.f};

        f16x8 aq[2][4];
        #define ALOAD(S, KS) do { \
            aq[S][0] = *(const f16x8*)(rp[0] + (size_t)(KS) * 16384); \
            aq[S][1] = *(const f16x8*)(rp[1] + (size_t)(KS) * 16384); \
            aq[S][2] = *(const f16x8*)(rp[2] + (size_t)(KS) * 16384); \
            aq[S][3] = *(const f16x8*)(rp[3] + (size_t)(KS) * 16384); \
        } while (0)
        ALOAD(0, 0); ALOAD(1, 1);
        #pragma unroll
        for (int ks = 0; ks < 16; ks++) {
            f16x8 a0 = aq[ks & 1][0], a1 = aq[ks & 1][1];
            f16x8 a2 = aq[ks & 1][2], a3 = aq[ks & 1][3];
            if (ks < 14) { ALOAD(ks & 1, ks + 2); }
            const uint32_t kadd = (uint32_t)((ks >> 2) << 8);
            const uint32_t kxor = (uint32_t)((ks & 3) << 6);
            #pragma unroll
            for (int g = 0; g < 3; g++) {
                f16x8 b = *(const f16x8*)(smem + ((bbase[g] + kadd) ^ kxor));
                acc[0][g] = __builtin_amdgcn_mfma_f32_16x16x32_f16(a0, b, acc[0][g], 0, 0, 0);
                acc[1][g] = __builtin_amdgcn_mfma_f32_16x16x32_f16(a1, b, acc[1][g], 0, 0, 0);
                acc[2][g] = __builtin_amdgcn_mfma_f32_16x16x32_f16(a2, b, acc[2][g], 0, 0, 0);
                acc[3][g] = __builtin_amdgcn_mfma_f32_16x16x32_f16(a3, b, acc[3][g], 0, 0, 0);
            }
        }
        #undef ALOAD

        // prologue (after GEMM issue): x_t for wave's 64 rows; dout_{t-1}
        {
            float v0, v1;
            if (t == 0) {
                v0 = xbuf[(size_t)(M0g + r0 + (lane >> 1)) * 2 + (lane & 1)];
                v1 = xbuf[(size_t)(M0g + r0 + 32 + (lane >> 1)) * 2 + (lane & 1)];
            } else {
                const float* pp = &g_P[t - 1][0] + (size_t)grp * 16384 + (size_t)r0 * 2 + lane;
                v0 = bo; v1 = bo;
                #pragma unroll
                for (int c = 0; c < 32; c++) { v0 += pp[c * 512]; v1 += pp[c * 512 + 64]; }
                if (cgrp == 0) {
                    dout[((size_t)(M0g + r0 + (lane >> 1)) * 12 + (t - 1)) * 2 + (lane & 1)] = v0;
                    dout[((size_t)(M0g + r0 + 32 + (lane >> 1)) * 12 + (t - 1)) * 2 + (lane & 1)] = v1;
                }
            }
            *(float*)(smem + XSO + (uint32_t)(wv * 512 + lane * 4)) = v0;
            *(float*)(smem + XSO + (uint32_t)(wv * 512 + 256 + lane * 4)) = v1;
        }

        // epilogue: gates (gi in regs), hn -> hstore, reduce -> g_P[t]
        #pragma unroll
        for (int mt = 0; mt < 4; mt++) {
            #pragma unroll
            for (int reg = 0; reg < 4; reg++) {
                int rl = mt * 16 + q2 * 4 + reg;
                float2 xv = *(const float2*)(smem + XSO + (uint32_t)(wv * 512 + rl * 8));
                _Float16* hp = (_Float16*)(smem + HST + (uint32_t)(wv * 2048 + rl * 32 + l15 * 2));
                float hold = (float)hp[0];
                float r  = sigm_f(gi0[mt][reg] + p0v.x * xv.x + p0v.y * xv.y + acc[mt][0][reg] + p1v.z);
                float u  = sigm_f(gi1[mt][reg] + p0v.z * xv.x + p0v.w * xv.y + acc[mt][1][reg] + p1v.w);
                float nn = tanh_f(gi2[mt][reg] + p1v.x * xv.x + p1v.y * xv.y + r * (acc[mt][2][reg] + p2v.x));
                float hn = (1.f - u) * nn + u * hold;
                hp[0] = (_Float16)hn;
                float a0 = hn * wo0, a1 = hn * wo1;
                a0 += __shfl_xor(a0, 1);  a1 += __shfl_xor(a1, 1);
                a0 += __shfl_xor(a0, 2);  a1 += __shfl_xor(a1, 2);
                a0 += __shfl_xor(a0, 4);  a1 += __shfl_xor(a1, 4);
                a0 += __shfl_xor(a0, 8);  a1 += __shfl_xor(a1, 8);
                if (l15 == 0) {
                    float* pp = &g_P[t][0] + (size_t)grp * 16384 + (size_t)cgrp * 512 +
                                (size_t)(r0 + rl) * 2;
                    *(float2*)pp = make_float2(a0, a1);
                }
            }
        }

        // publish h (wave slice, contiguous)
        if (t < 11) {
            #pragma unroll
            for (int p = 0; p < 2; p++) {
                int row = (lane >> 1) + p * 32;
                f16x8 hv = *(const f16x8*)(smem + HST + (uint32_t)(wv * 2048 + row * 32 + (lane & 1) * 16));
                *(f16x8*)((char*)&g_h[t + 1][0] + (size_t)grp * 262144 + (size_t)cgrp * 8192 +
                          (size_t)(r0 + row) * 32 + (size_t)(lane & 1) * 16) = hv;
            }
        }
        wave_arrive_wait(grp);
    }

    // ---- final out_11 from g_P[11] ----
    if (cgrp == 0) {
        const float* pp = &g_P[11][0] + (size_t)grp * 16384 + (size_t)r0 * 2 + lane;
        float v0 = bo, v1 = bo;
        #pragma unroll
        for (int c = 0; c < 32; c++) { v0 += pp[c * 512]; v1 += pp[c * 512 + 64]; }
        dout[((size_t)(M0g + r0 + (lane >> 1)) * 12 + 11) * 2 + (lane & 1)] = v0;
        dout[((size_t)(M0g + r0 + 32 + (lane >> 1)) * 12 + 11) * 2 + (lane & 1)] = v1;
    }
}

extern "C" void kernel_launch(void* const* d_in, const int* in_sizes, int n_in,
                              void* d_out, int out_size, void* d_ws, size_t ws_size,
                              hipStream_t stream)
{
    const float* z     = (const float*)d_in[0];
    const float* x     = (const float*)d_in[1];
    const float* x0    = (const float*)d_in[2];
    const float* W_ia  = (const float*)d_in[3];
    const float* b_ia  = (const float*)d_in[4];
    const float* W_h0  = (const float*)d_in[5];
    const float* b_h0  = (const float*)d_in[6];
    const float* W_ih  = (const float*)d_in[7];
    const float* b_ih  = (const float*)d_in[8];
    const float* W_hh  = (const float*)d_in[9];
    const float* b_hh  = (const float*)d_in[10];
    const float* W_out = (const float*)d_in[11];
    const float* b_out = (const float*)d_in[12];
    float* dout = (float*)d_out;

    char* ws = (char*)d_ws;
    _Float16* zx16   = (_Float16*)(ws + 20971520);   // 2 MiB
    _Float16* wcat16 = (_Float16*)(ws + 23068672);   // 1 MiB
    _Float16* whh16  = (_Float16*)(ws + 24117248);   // 1.5 MiB
    float*    pk     = (float*)(ws + 25690112);      // 24 KiB
    float*    xbuf   = (float*)(ws + 25714688);      // 32 KiB

    static bool s_attr_done = false;
    if (!s_attr_done) {
        hipFuncSetAttribute((const void*)k2_wave,
                            hipFuncAttributeMaxDynamicSharedMemorySize, 86016);
        s_attr_done = true;
    }

    k0_prep<<<2048, 256, 0, stream>>>(z, x, x0, W_ia, b_ia, W_ih, W_hh, W_h0,
                                      W_out, b_hh, zx16, wcat16, whh16, pk, xbuf);
    k2_wave<<<256, 512, 86016, stream>>>(zx16, wcat16, whh16, pk, xbuf,
                                         b_h0, b_ih, dout, b_out);
}

// Round 10
// 268.247 us; speedup vs baseline: 2.3742x; 2.3742x over previous
//
#include <hip/hip_runtime.h>
#include <cstdint>
#include <cstddef>

// R15: R12 champion structure (16 blocks/group x 32 cols, XCD-local, block
// ticket barrier, gi-in-registers pre-GEMM, fresh step-indexed buffers) with:
//  1. BLOCK-MAJOR h/P layouts: publish region is 16KB contiguous per block ->
//     lines block-private and fully self-written (L1-safe, no cross-block RFO
//     sharing).
//  2. L2 WARMING: at step start, 2 waves prefetch the block's own g_h[t+1] /
//     g_P[t] lines (global_load_lds -> dummy LDS) so the write-allocate HBM
//     fetch happens under the GEMM, not at the barrier's vmcnt(0).
//  3. Fully wave-private steady loop (xs, epilogue, hstore, publish touch only
//     the wave's 32 rows) -> ZERO mid-step __syncthreads; waves drift so
//     epilogue VALU overlaps sibling-wave GEMM MFMA.
//  4. dout stashed in LDS, flushed once at the end; prologue P-loads issued
//     before the GEMM and summed after it.

typedef __attribute__((ext_vector_type(8))) _Float16 f16x8;
typedef __attribute__((ext_vector_type(4))) float floatx4;

__device__ unsigned g_cnt[8 * 64];     // per-XCD registration tickets
__device__ unsigned g_gbar[16 * 64];   // per-group barrier counters (padded)

// Block-major exchange buffers (outside workspace; step-indexed => fresh
// addresses within a launch, validated R10-R12):
// g_h[t]: [16 grp][16 cgrp][256 rows][32 cols] fp16 (cgrp slab = 16KB).
// g_P[t]: [16 grp][16 cgrp][512] f32 (block slab = 2KB).
__device__ __align__(256) _Float16 g_h[12][16 * 16 * 256 * 32];
__device__ __align__(256) float    g_P[12][16 * 16 * 512];

__device__ __forceinline__ float sigm_f(float v) { return 1.0f / (1.0f + __expf(-v)); }
__device__ __forceinline__ float tanh_f(float v) { return 2.0f / (1.0f + __expf(-2.0f * v)) - 1.0f; }

__device__ __forceinline__ void async16(void* lds, const void* g) {
    __builtin_amdgcn_global_load_lds(
        (const __attribute__((address_space(1))) void*)g,
        (__attribute__((address_space(3))) void*)lds, 16, 0, 0);
}

// Per-group barrier: EXACTLY 16 co-resident same-XCD blocks (validated R11/R12).
__device__ __forceinline__ void group_barrier16(unsigned gidx) {
    asm volatile("s_waitcnt vmcnt(0)" ::: "memory");
    __syncthreads();
    if (threadIdx.x == 0) {
        unsigned* ctr = &g_gbar[gidx * 64];
        unsigned t = __hip_atomic_fetch_add(ctr, 1u, __ATOMIC_RELAXED,
                                            __HIP_MEMORY_SCOPE_AGENT);
        unsigned target = (t & ~15u) + 16u;
        while (__hip_atomic_load(ctr, __ATOMIC_RELAXED,
                                 __HIP_MEMORY_SCOPE_AGENT) < target)
            __builtin_amdgcn_s_sleep(1);
    }
    __syncthreads();
}

// ---------------- K0: casts + packing + a0 (unchanged, validated) ----------------
__global__ __launch_bounds__(256) void k0_prep(
    const float* __restrict__ z, const float* __restrict__ x,
    const float* __restrict__ x0, const float* __restrict__ W_ia,
    const float* __restrict__ b_ia, const float* __restrict__ W_ih,
    const float* __restrict__ W_hh, const float* __restrict__ W_h0,
    const float* __restrict__ W_out, const float* __restrict__ b_hh,
    _Float16* __restrict__ zx16, _Float16* __restrict__ wcat16,
    _Float16* __restrict__ whh16, float* __restrict__ pk, float* __restrict__ xbuf)
{
    const int ZX = 4096 * 256, WC = 2048 * 256, WH = 1536 * 512, PKN = 512, XB = 4096 * 2;
    const int total = ZX + WC + WH + PKN + XB;
    for (int idx = blockIdx.x * 256 + threadIdx.x; idx < total; idx += gridDim.x * 256) {
        if (idx < ZX) {
            int i = idx >> 8, k = idx & 255;
            float v = (k < 128) ? z[i * 128 + k] : x[i * 128 + (k - 128)];
            zx16[idx] = (_Float16)v;
        } else if (idx < ZX + WC) {
            int j = idx - ZX;
            int n = j >> 8, k = j & 255;
            float v = (n < 512) ? W_h0[n * 256 + k] : W_ih[(n - 512) * 258 + k];
            wcat16[j] = (_Float16)v;
        } else if (idx < ZX + WC + WH) {
            int j = idx - ZX - WC;
            whh16[j] = (_Float16)W_hh[j];
        } else if (idx < ZX + WC + WH + PKN) {
            int jc = idx - ZX - WC - WH;
            float* o = pk + jc * 12;
            o[0] = W_ih[jc * 258 + 256];          o[1] = W_ih[jc * 258 + 257];
            o[2] = W_ih[(512 + jc) * 258 + 256];  o[3] = W_ih[(512 + jc) * 258 + 257];
            o[4] = W_ih[(1024 + jc) * 258 + 256]; o[5] = W_ih[(1024 + jc) * 258 + 257];
            o[6] = b_hh[jc]; o[7] = b_hh[512 + jc]; o[8] = b_hh[1024 + jc];
            o[9] = W_out[jc]; o[10] = W_out[512 + jc]; o[11] = 0.f;
        } else {
            int j = idx - ZX - WC - WH - PKN;
            int i = j >> 1, d = j & 1;
            float s = b_ia[d];
            #pragma unroll
            for (int k2 = 0; k2 < 4; k2++) s += x0[i * 4 + k2] * W_ia[d * 4 + k2];
            xbuf[j] = s;
        }
    }
}

// ---------------- K2: fused pre-GEMM + XCD-local persistent GRU ----------------
// LDS: B @0 (96KB steady; 64KB pre-phase overlap), hstore[256][32]h @98304
// (16KB), xs[8][64]f @114688 (2KB), douts[8][12][64]f @116736 (24KB),
// dummy @141312 (1KB), slot @142336. Request 142400 (>80KB => 1 blk/CU).
__global__ __launch_bounds__(512, 2) void k2_fused(
    const _Float16* __restrict__ zx16, const _Float16* __restrict__ wcat16,
    const _Float16* __restrict__ whh16, const float* __restrict__ pk,
    const float* __restrict__ xbuf, const float* __restrict__ b_h0,
    const float* __restrict__ b_ih, float* __restrict__ dout,
    const float* __restrict__ b_out)
{
    extern __shared__ __align__(16) char smem[];
    const uint32_t BOFF = 0, HST = 98304, XSO = 114688, DOUT = 116736,
                   DUM = 141312, SLO = 142336;
    const int tid = threadIdx.x;
    float* xs = (float*)(smem + XSO);
    float* douts = (float*)(smem + DOUT);

    // ---- XCD discovery + registration (1 blk/CU => exactly 32 blks/XCD) ----
    unsigned xcc;
    asm volatile("s_getreg_b32 %0, hwreg(HW_REG_XCC_ID)" : "=s"(xcc));
    xcc &= 7u;
    if (tid == 0) {
        unsigned s = __hip_atomic_fetch_add(&g_cnt[xcc * 64], 1u, __ATOMIC_RELAXED,
                                            __HIP_MEMORY_SCOPE_AGENT) & 31u;
        *(unsigned*)(smem + SLO) = s;
    }
    __syncthreads();
    const unsigned slot = *(volatile unsigned*)(smem + SLO);
    const int shalf = slot >> 4, cgrp = slot & 15;
    const unsigned gidx = xcc * 2 + shalf;      // 0..15, 16 blocks each
    const int M0g = (int)gidx * 256;            // group's global sample base
    const int jc0 = cgrp * 32;                  // block's 32 h-cols (x3 gates)

    const int wv = tid >> 6, lane = tid & 63;
    const int l15 = lane & 15, q2 = lane >> 4;

    // ---- warm g_h[0] + g_P[0] own regions (one-time RFO prefetch) ----
    if (wv == 0) {
        const char* wb = (const char*)&g_h[0][0] + (size_t)gidx * 262144 +
                         (size_t)cgrp * 16384 + (size_t)lane * 128;
        async16(smem + DUM, wb);
        async16(smem + DUM, wb + 8192);
    }
    if (wv == 1) {
        const char* wp = (const char*)&g_P[0][0] +
                         ((size_t)gidx * 8192 + (size_t)cgrp * 512) * 4 +
                         (size_t)(lane & 15) * 128;
        async16(smem + DUM, wp);
    }

    // ---- stage pre-B: 128 rows x 256 fp16 (512B) from wcat16 [R12] ----
    #pragma unroll
    for (int j2 = 0; j2 < 8; j2++) {
        int p = j2 * 8 + wv;              // 0..63 (wave-uniform)
        int r0 = p * 2;
        int r = r0 + (lane >> 5);
        int s = lane & 31;
        int n = (r < 96) ? (512 + (r >> 5) * 512 + jc0 + (r & 31))
                         : (jc0 + (r - 96));
        const _Float16* src = wcat16 + (size_t)n * 256 + ((s ^ (r & 15)) << 3);
        async16(smem + (uint32_t)r0 * 512, src);
    }

    // ---- t-invariant params [R12] ----
    float4 p0v[2], p1v[2], p2v[2]; float wo0[2], wo1[2];
    float bih[3][2], bh0[2];
    #pragma unroll
    for (int jt = 0; jt < 2; jt++) {
        int jc = jc0 + jt * 16 + l15;
        const float4* pkp = (const float4*)(pk + (size_t)jc * 12);
        p0v[jt] = pkp[0]; p1v[jt] = pkp[1]; p2v[jt] = pkp[2];
        wo0[jt] = p2v[jt].y; wo1[jt] = p2v[jt].z;
        bh0[jt] = b_h0[jc];
        #pragma unroll
        for (int g = 0; g < 3; g++) bih[g][jt] = b_ih[g * 512 + jc];
    }
    float bo = b_out[lane & 1];

    uint32_t bbase[6];   // steady B (96 rows x 1024B) [R12 swizzle]
    #pragma unroll
    for (int g = 0; g < 3; g++)
        #pragma unroll
        for (int jt = 0; jt < 2; jt++) {
            int r = g * 32 + jt * 16 + l15;
            bbase[g * 2 + jt] = BOFF + (uint32_t)r * 1024 +
                                ((uint32_t)(q2 ^ (r & 3)) << 4) +
                                ((uint32_t)((r >> 2) & 3) << 6);
        }
    uint32_t pb[8];      // pre-B (128 rows x 512B): 0..5 gates, 6..7 h0 [R12]
    #pragma unroll
    for (int sl = 0; sl < 8; sl++) {
        int r = (sl < 6) ? ((sl >> 1) * 32 + (sl & 1) * 16 + l15)
                         : (96 + (sl - 6) * 16 + l15);
        pb[sl] = BOFF + (uint32_t)r * 512 +
                 ((uint32_t)(q2 ^ (r & 3)) << 4) +
                 ((uint32_t)((r >> 2) & 3) << 6);
    }
    __syncthreads();   // pre-B staged (barrier drains vmcnt)

    // ---- pre-GEMM: K=256, A=zx16, 8 ks, depth-3 queue [R12 verbatim] ----
    const char* zp0 = (const char*)zx16 +
        ((size_t)(M0g + (wv * 2 + 0) * 16 + l15) * 256) * 2 + (size_t)q2 * 16;
    const char* zp1 = (const char*)zx16 +
        ((size_t)(M0g + (wv * 2 + 1) * 16 + l15) * 256) * 2 + (size_t)q2 * 16;
    floatx4 accP[2][8];
    #pragma unroll
    for (int mt = 0; mt < 2; mt++)
        #pragma unroll
        for (int sl = 0; sl < 8; sl++) accP[mt][sl] = (floatx4){0.f, 0.f, 0.f, 0.f};
    {
        f16x8 aq[4][2];
        #define ALOADZ(S, KS) do { \
            aq[S][0] = *(const f16x8*)(zp0 + (KS) * 64); \
            aq[S][1] = *(const f16x8*)(zp1 + (KS) * 64); \
        } while (0)
        ALOADZ(0, 0); ALOADZ(1, 1); ALOADZ(2, 2);
        #pragma unroll
        for (int ks = 0; ks < 8; ks++) {
            if (ks < 5) { ALOADZ((ks + 3) & 3, ks + 3); }
            f16x8 a0 = aq[ks & 3][0];
            f16x8 a1 = aq[ks & 3][1];
            const uint32_t kadd = (uint32_t)((ks >> 2) << 8);
            const uint32_t kxor = (uint32_t)((ks & 3) << 6);
            #pragma unroll
            for (int sl = 0; sl < 8; sl++) {
                f16x8 b = *(const f16x8*)(smem + ((pb[sl] + kadd) ^ kxor));
                accP[0][sl] = __builtin_amdgcn_mfma_f32_16x16x32_f16(a0, b, accP[0][sl], 0, 0, 0);
                accP[1][sl] = __builtin_amdgcn_mfma_f32_16x16x32_f16(a1, b, accP[1][sl], 0, 0, 0);
            }
        }
        #undef ALOADZ
    }

    // ---- gi -> registers (+bias); h0 -> hstore [R12] ----
    float gi[2][3][2][4];
    #pragma unroll
    for (int mt = 0; mt < 2; mt++)
        #pragma unroll
        for (int g = 0; g < 3; g++)
            #pragma unroll
            for (int jt = 0; jt < 2; jt++)
                #pragma unroll
                for (int reg = 0; reg < 4; reg++)
                    gi[mt][g][jt][reg] = accP[mt][g * 2 + jt][reg] + bih[g][jt];
    #pragma unroll
    for (int mt = 0; mt < 2; mt++)
        #pragma unroll
        for (int jt = 0; jt < 2; jt++)
            #pragma unroll
            for (int reg = 0; reg < 4; reg++) {
                int rl = (wv * 2 + mt) * 16 + q2 * 4 + reg;
                float v = accP[mt][6 + jt][reg] + bh0[jt];
                *(_Float16*)(smem + HST + (uint32_t)(rl * 64 + (jt * 16 + l15) * 2)) = (_Float16)v;
            }
    __syncthreads();   // pre-B reads + hstore writes complete

    // ---- stage W_hh (96 rows x 512 = 96KB) [R12] ----
    #pragma unroll
    for (int j = 0; j < 12; j++) {
        int r = j * 8 + wv;               // 0..95
        int n = (r >> 5) * 512 + jc0 + (r & 31);
        const _Float16* src = whh16 + (size_t)n * 512 + ((lane ^ (r & 15)) << 3);
        async16(smem + BOFF + (uint32_t)r * 1024, src);
    }
    // ---- publish h0 (block-major, contiguous own lines) ----
    {
        int row = tid >> 1, half = tid & 1;
        const char* sl = smem + HST + (uint32_t)(row * 64 + half * 32);
        char* gd = (char*)&g_h[0][0] + (size_t)gidx * 262144 + (size_t)cgrp * 16384 +
                   (size_t)row * 64 + (size_t)half * 32;
        *(f16x8*)gd = *(const f16x8*)sl;
        *(f16x8*)(gd + 16) = *(const f16x8*)(sl + 16);
    }
    group_barrier16(gidx);   // drains W_hh staging + h0 publish

    // ---- 12-step loop: no mid-step __syncthreads ----
    #pragma unroll 1
    for (int t = 0; t < 12; t++) {
        // warm next-step publish regions (RFO prefetch, overlapped with GEMM)
        if (t < 11 && wv == 0) {
            const char* wb = (const char*)&g_h[t + 1][0] + (size_t)gidx * 262144 +
                             (size_t)cgrp * 16384 + (size_t)lane * 128;
            async16(smem + DUM, wb);
            async16(smem + DUM, wb + 8192);
        }
        if (wv == 1) {
            const char* wp = (const char*)&g_P[t][0] +
                             ((size_t)gidx * 8192 + (size_t)cgrp * 512) * 4 +
                             (size_t)(lane & 15) * 128;
            async16(smem + DUM, wp);
        }

        // GEMM: K=512, A from g_h[t] (block-major: ks slab = 16KB)
        const char* hb = (const char*)&g_h[t][0] + (size_t)gidx * 262144 + (size_t)q2 * 16;
        const char* rp0 = hb + (size_t)((wv * 2 + 0) * 16 + l15) * 64;
        const char* rp1 = hb + (size_t)((wv * 2 + 1) * 16 + l15) * 64;
        floatx4 acc[2][3][2];
        #pragma unroll
        for (int mt = 0; mt < 2; mt++)
            #pragma unroll
            for (int g = 0; g < 3; g++)
                #pragma unroll
                for (int jt = 0; jt < 2; jt++)
                    acc[mt][g][jt] = (floatx4){0.f, 0.f, 0.f, 0.f};

        f16x8 aq[4][2];
        #define ALOAD(S, KS) do { \
            aq[S][0] = *(const f16x8*)(rp0 + (size_t)(KS) * 16384); \
            aq[S][1] = *(const f16x8*)(rp1 + (size_t)(KS) * 16384); \
        } while (0)
        ALOAD(0, 0); ALOAD(1, 1); ALOAD(2, 2);

        // prologue loads issued early (consumed after GEMM)
        float pv[16];
        if (t > 0) {
            const float* pbase = &g_P[t - 1][0] + (size_t)gidx * 8192 +
                                 (size_t)(wv * 32 + (lane >> 1)) * 2 + (size_t)(lane & 1);
            #pragma unroll
            for (int c = 0; c < 16; c++) pv[c] = pbase[c * 512];
        }

        #pragma unroll
        for (int ks = 0; ks < 16; ks++) {
            if (ks < 13) { ALOAD((ks + 3) & 3, ks + 3); }
            f16x8 a0 = aq[ks & 3][0];
            f16x8 a1 = aq[ks & 3][1];
            const uint32_t kadd = (uint32_t)((ks >> 2) << 8);
            const uint32_t kxor = (uint32_t)((ks & 3) << 6);
            #pragma unroll
            for (int g = 0; g < 3; g++)
                #pragma unroll
                for (int jt = 0; jt < 2; jt++) {
                    f16x8 b = *(const f16x8*)(smem + ((bbase[g * 2 + jt] + kadd) ^ kxor));
                    acc[0][g][jt] = __builtin_amdgcn_mfma_f32_16x16x32_f16(a0, b, acc[0][g][jt], 0, 0, 0);
                    acc[1][g][jt] = __builtin_amdgcn_mfma_f32_16x16x32_f16(a1, b, acc[1][g][jt], 0, 0, 0);
                }
        }
        #undef ALOAD

        // prologue finish (wave-private): x_t for wave's 32 rows
        {
            float v;
            if (t == 0) {
                v = xbuf[(size_t)(M0g + wv * 32 + (lane >> 1)) * 2 + (lane & 1)];
            } else {
                v = bo;
                #pragma unroll
                for (int c = 0; c < 16; c++) v += pv[c];
                douts[wv * 768 + (t - 1) * 64 + lane] = v;   // stash out_{t-1}
            }
            xs[wv * 64 + lane] = v;
        }

        // epilogue (wave-private rows): gates, hn -> hstore, reduce -> g_P[t]
        #pragma unroll
        for (int mt = 0; mt < 2; mt++) {
            float po[4][2];
            #pragma unroll
            for (int reg = 0; reg < 4; reg++) { po[reg][0] = 0.f; po[reg][1] = 0.f; }
            #pragma unroll
            for (int jt = 0; jt < 2; jt++) {
                #pragma unroll
                for (int reg = 0; reg < 4; reg++) {
                    int local = mt * 16 + q2 * 4 + reg;        // 0..31 in wave
                    int rl = wv * 32 + local;                  // 0..255 in block
                    float2 xv = *(const float2*)(smem + XSO + (uint32_t)((wv * 64 + local * 2) * 4));
                    _Float16* hp = (_Float16*)(smem + HST + (uint32_t)(rl * 64 + (jt * 16 + l15) * 2));
                    float hold = (float)hp[0];
                    float r  = sigm_f(gi[mt][0][jt][reg] + p0v[jt].x * xv.x + p0v[jt].y * xv.y + acc[mt][0][jt][reg] + p1v[jt].z);
                    float u  = sigm_f(gi[mt][1][jt][reg] + p0v[jt].z * xv.x + p0v[jt].w * xv.y + acc[mt][1][jt][reg] + p1v[jt].w);
                    float nn = tanh_f(gi[mt][2][jt][reg] + p1v[jt].x * xv.x + p1v[jt].y * xv.y + r * (acc[mt][2][jt][reg] + p2v[jt].x));
                    float hn = (1.f - u) * nn + u * hold;
                    hp[0] = (_Float16)hn;
                    po[reg][0] += hn * wo0[jt];
                    po[reg][1] += hn * wo1[jt];
                }
            }
            #pragma unroll
            for (int m = 1; m < 16; m <<= 1)
                #pragma unroll
                for (int reg = 0; reg < 4; reg++) {
                    po[reg][0] += __shfl_xor(po[reg][0], m);
                    po[reg][1] += __shfl_xor(po[reg][1], m);
                }
            if (l15 == 0) {
                #pragma unroll
                for (int reg = 0; reg < 4; reg++) {
                    int local = mt * 16 + q2 * 4 + reg;
                    float* pp = &g_P[t][0] + (size_t)gidx * 8192 + (size_t)cgrp * 512 +
                                (size_t)(wv * 32 + local) * 2;
                    *(float2*)pp = make_float2(po[reg][0], po[reg][1]);
                }
            }
        }

        // publish h (wave-private 2KB slice, block-major contiguous)
        if (t < 11) {
            int rloc = wv * 32 + (lane >> 1);
            int half = lane & 1;
            const char* sl = smem + HST + (uint32_t)(rloc * 64 + half * 32);
            char* gd = (char*)&g_h[t + 1][0] + (size_t)gidx * 262144 +
                       (size_t)cgrp * 16384 + (size_t)rloc * 64 + (size_t)half * 32;
            *(f16x8*)gd = *(const f16x8*)sl;
            *(f16x8*)(gd + 16) = *(const f16x8*)(sl + 16);
        }
        group_barrier16(gidx);
    }

    // ---- final: out_11 + dout flush (cgrp 0 blocks only) ----
    if (cgrp == 0) {
        const float* pbase = &g_P[11][0] + (size_t)gidx * 8192 +
                             (size_t)(wv * 32 + (lane >> 1)) * 2 + (size_t)(lane & 1);
        float v = bo;
        #pragma unroll
        for (int c = 0; c < 16; c++) v += pbase[c * 512];
        douts[wv * 768 + 11 * 64 + lane] = v;
        size_t i = (size_t)(M0g + wv * 32 + (lane >> 1));
        int d = lane & 1;
        #pragma unroll
        for (int t = 0; t < 12; t++)
            dout[(i * 12 + t) * 2 + d] = douts[wv * 768 + t * 64 + lane];
    }
}

extern "C" void kernel_launch(void* const* d_in, const int* in_sizes, int n_in,
                              void* d_out, int out_size, void* d_ws, size_t ws_size,
                              hipStream_t stream)
{
    const float* z     = (const float*)d_in[0];
    const float* x     = (const float*)d_in[1];
    const float* x0    = (const float*)d_in[2];
    const float* W_ia  = (const float*)d_in[3];
    const float* b_ia  = (const float*)d_in[4];
    const float* W_h0  = (const float*)d_in[5];
    const float* b_h0  = (const float*)d_in[6];
    const float* W_ih  = (const float*)d_in[7];
    const float* b_ih  = (const float*)d_in[8];
    const float* W_hh  = (const float*)d_in[9];
    const float* b_hh  = (const float*)d_in[10];
    const float* W_out = (const float*)d_in[11];
    const float* b_out = (const float*)d_in[12];
    float* dout = (float*)d_out;

    char* ws = (char*)d_ws;
    _Float16* zx16   = (_Float16*)(ws + 20971520);   // 2 MiB
    _Float16* wcat16 = (_Float16*)(ws + 23068672);   // 1 MiB
    _Float16* whh16  = (_Float16*)(ws + 24117248);   // 1.5 MiB
    float*    pk     = (float*)(ws + 25690112);      // 24 KiB
    float*    xbuf   = (float*)(ws + 25714688);      // 32 KiB

    static bool s_attr_done = false;
    if (!s_attr_done) {
        hipFuncSetAttribute((const void*)k2_fused,
                            hipFuncAttributeMaxDynamicSharedMemorySize, 142400);
        s_attr_done = true;
    }

    k0_prep<<<2048, 256, 0, stream>>>(z, x, x0, W_ia, b_ia, W_ih, W_hh, W_h0,
                                      W_out, b_hh, zx16, wcat16, whh16, pk, xbuf);
    k2_fused<<<256, 512, 142400, stream>>>(zx16, wcat16, whh16, pk, xbuf,
                                           b_h0, b_ih, dout, b_out);
}